// Round 3
// baseline (875.408 us; speedup 1.0000x reference)
//
#include <hip/hip_runtime.h>
#include <hip/hip_bf16.h>
#include <math.h>

// Problem constants
#define BN   16
#define NCH  64      // CIN == COUT == 64
#define HH   256
#define WW   256
#define M0_  20
#define M1_  20

// Workspace layout (in floats)
#define TWA_OFF 0
#define TWA_SZ  (256*40)            // bf16 twA_T[48][256] (uses 6144 float slots)
#define TWB_OFF (TWA_OFF + TWA_SZ)
#define TWB_SZ  (20*256*2)          // [k][h] (cos, -sin)/256 pairs (fp32)
#define TRG_OFF (TWB_OFF + TWB_SZ)
#define TRG_SZ  (256*20)            // trigT[w][l] packed bf16 (cos,-sin) dwords, 20KB
#define X_OFF   (TRG_OFF + TRG_SZ)
#define X_SZ    (1024*800)          // [b*64+i][k*20+l] complex fp32
#define OF_OFF  (X_OFF + X_SZ)
#define OF_SZ   (1024*800)          // [b*64+o][k*20+l] complex fp32 (scaled)
#define Z_OFF   (OF_OFF + OF_SZ)
#define Z_SZ    (1024*256*20)       // Zpk: [b*64+o][h][l] packed bf16 (zr,zi) dwords

// ---------------- shared helpers (bf16 pack) ----------------
typedef __attribute__((ext_vector_type(8))) short short8;
typedef __attribute__((ext_vector_type(4))) float f32x4;
union FI4 { int4 i; short8 s; uint4 u; };

__device__ __forceinline__ unsigned short bfh(float f){
  union { float f; unsigned u; } v; v.f = f;
  unsigned r = v.u + 0x7FFFu + ((v.u >> 16) & 1u);   // RNE to bf16
  return (unsigned short)(r >> 16);
}
__device__ __forceinline__ float bf2f(unsigned short s){
  union { unsigned u; float f; } v; v.u = ((unsigned)s) << 16;
  return v.f;
}
__device__ __forceinline__ unsigned pk2(float e, float o){   // e -> low short, o -> high short
  return (unsigned)bfh(e) | ((unsigned)bfh(o) << 16);
}
__device__ __forceinline__ short8 pack8hi(float4 a, float4 b){  // 8 floats -> 8 bf16 in order
  FI4 r;
  r.i.x = (int)pk2(a.x, a.y); r.i.y = (int)pk2(a.z, a.w);
  r.i.z = (int)pk2(b.x, b.y); r.i.w = (int)pk2(b.z, b.w);
  return r.s;
}
__device__ __forceinline__ float lof(float f){ return f - bf2f(bfh(f)); }
__device__ __forceinline__ short8 pack8lo(float4 a, float4 b){
  FI4 r;
  r.i.x = (int)pk2(lof(a.x), lof(a.y)); r.i.y = (int)pk2(lof(a.z), lof(a.w));
  r.i.z = (int)pk2(lof(b.x), lof(b.y)); r.i.w = (int)pk2(lof(b.z), lof(b.w));
  return r.s;
}

// ---------------- twiddle tables ----------------
// twA:  bf16 twA_T[j=48][w=256]; j=2l+p: p=0 -> cos(2pi*w*l/256), p=1 -> -sin; rows 40..47 = 0
// twB:  fp32 [k][h] (cos,-sin)/256 pairs (forward-h DFT, ortho fold)
// trigT: dword[w=256][l=20] = pk2(cos(2pi*l*w/256), -sin(2pi*l*w/256))  (k_out B-side)
__global__ __launch_bounds__(256) void k_init(float* __restrict__ twA, float* __restrict__ twB,
                                              unsigned* __restrict__ trigT){
  int t = blockIdx.x*256 + threadIdx.x;      // 5120 threads
  const float step = 6.28318530717958647692f / 256.0f;
  if (t < 5120){
    int k = t >> 8, h = t & 255;
    int m = (k*h) & 255;
    float a = step * (float)m;
    twB[2*t]   =  cosf(a) * (1.0f/256.0f);
    twB[2*t+1] = -sinf(a) * (1.0f/256.0f);
  }
  if (t < 5120){
    int w = t / 20, l = t - (t/20)*20;
    int m = (w*l) & 255;
    float a = step * (float)m;
    trigT[w*20 + l] = pk2(cosf(a), -sinf(a));
  }
  unsigned short* ta = (unsigned short*)twA;
  for (int idx = t; idx < 48*256; idx += 5120){
    int j = idx >> 8, w = idx & 255;
    float v = 0.f;
    if (j < 40){
      int l = j >> 1;
      int m = (w*l) & 255;
      float a = step * (float)m;
      v = (j & 1) ? -sinf(a) : cosf(a);
    }
    ta[idx] = bfh(v);
  }
}

// ---------------- fused forward transform (MFMA w-DFT + VALU h-DFT) ----------------
__global__ __launch_bounds__(256, 3) void k_fwd(const float* __restrict__ x,
                                                const float* __restrict__ twA,
                                                const float* __restrict__ twB,
                                                float* __restrict__ X){
  __shared__ float Y[256*50];     // 50 KB -> 3 blocks/CU

  const int t = threadIdx.x;
  const int lane = t & 63, wv = t >> 6;
  const int g = lane >> 4, rA = lane & 15;
  const int bi = blockIdx.x;

  const unsigned short* ta = (const unsigned short*)twA;
  const float* xb = x + (size_t)bi * 65536;

#pragma unroll 1
  for (int q = 0; q < 4; ++q){
    int mt = wv*4 + q;
    const float* xr = xb + (size_t)(mt*16 + rA)*256 + g*8;
    short8 As[8];
#pragma unroll
    for (int ks = 0; ks < 8; ++ks){
      float4 a = *(const float4*)(xr + ks*32);
      float4 b = *(const float4*)(xr + ks*32 + 4);
      As[ks] = pack8hi(a, b);
    }
    f32x4 acc[3];
#pragma unroll
    for (int n = 0; n < 3; ++n){ f32x4 z; z[0]=0.f; z[1]=0.f; z[2]=0.f; z[3]=0.f; acc[n] = z; }
#pragma unroll
    for (int ks = 0; ks < 8; ++ks){
#pragma unroll
      for (int n = 0; n < 3; ++n){
        short8 Bf = *(const short8*)(ta + ((n*16 + rA)*256 + ks*32 + g*8));  // L1/L2-resident
        acc[n] = __builtin_amdgcn_mfma_f32_16x16x32_bf16(As[ks], Bf, acc[n], 0, 0, 0);
      }
    }
#pragma unroll
    for (int n = 0; n < 3; ++n)
#pragma unroll
      for (int r = 0; r < 4; ++r)
        Y[(mt*16 + g*4 + r)*50 + n*16 + rA] = acc[n][r];
  }
  __syncthreads();

  // stage 2: h-DFT (20 modes), ortho 1/256 folded in twB
  const float2* tb2 = (const float2*)twB;
  for (int it = t; it < 400; it += 256){
    int k = it / 20, l = it - k*20;
    const float2* tb = tb2 + k*256;
    float are = 0.f, aim = 0.f;
#pragma unroll 4
    for (int h = 0; h < 256; ++h){
      float2 tv = tb[h];
      float2 yv = *(const float2*)&Y[h*50 + 2*l];
      are += yv.x*tv.x - yv.y*tv.y;
      aim += yv.x*tv.y + yv.y*tv.x;
    }
    ((float2*)X)[(size_t)bi*400 + it] = make_float2(are, aim);
  }
}

// ---------------- stage C: per-mode channel mix ----------------
__global__ __launch_bounds__(256) void k_mix(const float* __restrict__ X,
                                             const float* __restrict__ wre,
                                             const float* __restrict__ wim,
                                             float* __restrict__ OF){
  __shared__ float2 Xs[1024];
  int bk = blockIdx.x;
  int kl = (bk & 7)*50 + (bk >> 3);
  const float2* X2 = (const float2*)X;
  for (int r = threadIdx.x; r < 1024; r += 256) Xs[r] = X2[(size_t)r*400 + kl];
  __syncthreads();
  int o = threadIdx.x & 63, bg = threadIdx.x >> 6;
  float ar[4] = {0,0,0,0}, ai[4] = {0,0,0,0};
  for (int i=0;i<64;++i){
    size_t widx = (size_t)(i*64 + o)*400 + kl;
    float wr = wre[widx], wi = wim[widx];
#pragma unroll
    for (int j=0;j<4;j++){
      float2 xv = Xs[(bg*4+j)*64 + i];
      ar[j] += xv.x*wr - xv.y*wi;
      ai[j] += xv.x*wi + xv.y*wr;
    }
  }
  int l = kl % 20;
  float scale = (l==0 ? 1.0f : 2.0f) * (1.0f/256.0f);
  float2* OF2 = (float2*)OF;
#pragma unroll
  for (int j=0;j<4;j++){
    OF2[(size_t)((bg*4+j)*64 + o)*400 + kl] = make_float2(ar[j]*scale, ai[j]*scale);
  }
}

// ---------------- stage D: zero-padded inverse DFT along h -> packed bf16 Z ----------------
__global__ __launch_bounds__(256) void k_idfth(const float* __restrict__ OF,
                                               unsigned* __restrict__ Zpk){
  __shared__ float2 fs[400];
  int bo = blockIdx.x;
  const float2* src = ((const float2*)OF) + (size_t)bo*400;
  for (int r = threadIdx.x; r < 400; r += 256) fs[r] = src[r];
  __syncthreads();
  int h = threadIdx.x;
  float s1, c1;
  sincosf((float)h * 0.02454369260617025967f, &s1, &c1);
  float zr[20], zi[20];
#pragma unroll
  for (int l=0;l<20;l++){ zr[l]=0.f; zi[l]=0.f; }
  float tr = 1.f, ti = 0.f;
  for (int k=0;k<20;++k){
#pragma unroll
    for (int l=0;l<20;l++){
      float2 f = fs[k*20+l];
      zr[l] += f.x*tr - f.y*ti;
      zi[l] += f.x*ti + f.y*tr;
    }
    float nt = tr*c1 - ti*s1;
    ti = tr*s1 + ti*c1;
    tr = nt;
  }
  // write packed bf16 (zr,zi) dwords: dword l = pk2(zr[l], zi[l]); 80B/thread, contiguous per wave
  unsigned* dst = Zpk + ((size_t)bo*256 + h)*20;
#pragma unroll
  for (int p=0;p<5;p++){
    uint4 v;
    v.x = pk2(zr[4*p+0], zi[4*p+0]);
    v.y = pk2(zr[4*p+1], zi[4*p+1]);
    v.z = pk2(zr[4*p+2], zi[4*p+2]);
    v.w = pk2(zr[4*p+3], zi[4*p+3]);
    *(uint4*)(dst + 4*p) = v;
  }
}

// ---------------- stage E (MFMA): conv(hi+lo) + spectral irfft-w + GELU ----------------
// Per block (b,h):  D[o,w] = sum_k A[o,k]*B[k,w] + cb[o],  K = 192
//   kt0,1 : cw_hi x-rows     kt2,3 : cw_lo x-rows     kt4,5 : Zpk vs trigT rows
// LDS: only the 32 packed-x rows (32 KB). Trig B-side from global trigT (L1-resident).
__global__ __launch_bounds__(256, 4) void k_out(const float* __restrict__ x,
                                                const unsigned* __restrict__ Zpk,
                                                const unsigned* __restrict__ trigT,
                                                const float* __restrict__ cw,
                                                const float* __restrict__ cb,
                                                float* __restrict__ out){
  __shared__ unsigned xp[32*256];   // 32 KB -> 5 blocks/CU (LDS-wise)

  const int t    = threadIdx.x;
  const int lane = t & 63, wv = t >> 6;
  const int b = blockIdx.x >> 8, h = blockIdx.x & 255;

  const float* xb = x + ((size_t)b*64*65536 + (size_t)h*256);

  // ---- stage x[b,:,h,:] as packed bf16 k-pairs (row i2 = i/2) ----
#pragma unroll
  for (int p = 0; p < 8; ++p){
    int i2 = p*4 + wv;             // 0..31
    int w0 = lane*4;               // wave covers full 1KB row
    float4 r0 = *(const float4*)(xb + (size_t)(2*i2)  *65536 + w0);
    float4 r1 = *(const float4*)(xb + (size_t)(2*i2+1)*65536 + w0);
    uint4 d;
    d.x = pk2(r0.x, r1.x);
    d.y = pk2(r0.y, r1.y);
    d.z = pk2(r0.z, r1.z);
    d.w = pk2(r0.w, r1.w);
    int col = (w0 + 4*i2) & 255;   // swizzle: multiple of 4 -> 16B aligned
    *(uint4*)&xp[i2*256 + col] = d;
  }
  __syncthreads();

  const int g = lane >> 4, rA = lane & 15;

  // accumulators init with bias: C row o = 16*mt + 4*g + r
  f32x4 acc[4][4];
#pragma unroll
  for (int mt = 0; mt < 4; ++mt){
    float4 cbv = *(const float4*)(cb + mt*16 + g*4);
#pragma unroll
    for (int j = 0; j < 4; ++j){
      f32x4 a0; a0[0] = cbv.x; a0[1] = cbv.y; a0[2] = cbv.z; a0[3] = cbv.w;
      acc[j][mt] = a0;
    }
  }

#pragma unroll
  for (int pass = 0; pass < 2; ++pass){
    // ---- A fragments for this pass (row o = 16*mt + rA, k-octet by g) ----
    short8 As[4][3];
    if (pass == 0){
#pragma unroll
      for (int mt = 0; mt < 4; ++mt){
        const float* cwo = cw + (size_t)(mt*16 + rA)*64;
        float4 c0a = *(const float4*)(cwo + 8*g);
        float4 c0b = *(const float4*)(cwo + 8*g + 4);
        float4 c1a = *(const float4*)(cwo + 32 + 8*g);
        float4 c1b = *(const float4*)(cwo + 32 + 8*g + 4);
        As[mt][0] = pack8hi(c0a, c0b);   // kt0: cw_hi, i = 8g..8g+7   (B = x rows 0..15)
        As[mt][1] = pack8hi(c1a, c1b);   // kt1: cw_hi, i = 32+8g..    (B = x rows 16..31)
        As[mt][2] = pack8lo(c0a, c0b);   // kt2: cw_lo, i = 8g..       (B = x rows 0..15)
      }
    } else {
#pragma unroll
      for (int mt = 0; mt < 4; ++mt){
        const float* cwo = cw + (size_t)(mt*16 + rA)*64;
        float4 c1a = *(const float4*)(cwo + 32 + 8*g);
        float4 c1b = *(const float4*)(cwo + 32 + 8*g + 4);
        As[mt][0] = pack8lo(c1a, c1b);   // kt3: cw_lo, i = 32+8g..    (B = x rows 16..31)
        const unsigned* zo = Zpk + ((size_t)(b*64 + mt*16 + rA)*256 + h)*20;
        FI4 z0; z0.u = *(const uint4*)(zo + 4*g);   // (zr,zi) l = 4g..4g+3, pre-packed bf16
        As[mt][1] = z0.s;                // kt4 (B = trig rows l=4g..4g+3)
        FI4 z1; z1.u = *(const uint4*)(zo + 16);    // l = 16..19 (all lanes; used iff g==0)
        if (g != 0){ z1.i.x = 0; z1.i.y = 0; z1.i.z = 0; z1.i.w = 0; }
        As[mt][2] = z1.s;                // kt5 (zero-pad k beyond 168 via A=0)
      }
    }
    // ---- main MFMA loop: wave wv owns n-tiles wv*4 .. wv*4+3 ----
#pragma unroll
    for (int j = 0; j < 4; ++j){
      int w = (wv*4 + j)*16 + rA;        // B col n = lane&15
      // x-row B fragments (shared between hi and lo k-tiles)
      FI4 bx;
#pragma unroll
      for (int e2 = 0; e2 < 4; ++e2){
        int k2 = (pass ? 16 : 0) + 4*g + e2;
        (&bx.i.x)[e2] = (int)xp[k2*256 + ((w + 4*k2) & 255)];
      }
      if (pass == 0){
        FI4 bx1;
#pragma unroll
        for (int e2 = 0; e2 < 4; ++e2){
          int k2 = 16 + 4*g + e2;
          (&bx1.i.x)[e2] = (int)xp[k2*256 + ((w + 4*k2) & 255)];
        }
#pragma unroll
        for (int mt = 0; mt < 4; ++mt){
          acc[j][mt] = __builtin_amdgcn_mfma_f32_16x16x32_bf16(As[mt][0], bx.s,  acc[j][mt], 0, 0, 0);
          acc[j][mt] = __builtin_amdgcn_mfma_f32_16x16x32_bf16(As[mt][1], bx1.s, acc[j][mt], 0, 0, 0);
          acc[j][mt] = __builtin_amdgcn_mfma_f32_16x16x32_bf16(As[mt][2], bx.s,  acc[j][mt], 0, 0, 0);
        }
      } else {
        FI4 bt0; bt0.u = *(const uint4*)(trigT + w*20 + 4*g);  // trig l = 4g..4g+3 (L1-resident)
        FI4 bt1; bt1.u = *(const uint4*)(trigT + w*20 + 16);   // trig l = 16..19
#pragma unroll
        for (int mt = 0; mt < 4; ++mt){
          acc[j][mt] = __builtin_amdgcn_mfma_f32_16x16x32_bf16(As[mt][0], bx.s,   acc[j][mt], 0, 0, 0);
          acc[j][mt] = __builtin_amdgcn_mfma_f32_16x16x32_bf16(As[mt][1], bt0.s,  acc[j][mt], 0, 0, 0);
          acc[j][mt] = __builtin_amdgcn_mfma_f32_16x16x32_bf16(As[mt][2], bt1.s,  acc[j][mt], 0, 0, 0);
        }
      }
    }
  }

  // ---- epilogue: GELU + store (C: col w = 16nt + lane&15, row o = 16mt + 4g + r) ----
  float* ob = out + ((size_t)b*64*65536 + (size_t)h*256);
#pragma unroll
  for (int j = 0; j < 4; ++j){
    int w = (wv*4 + j)*16 + rA;
#pragma unroll
    for (int mt = 0; mt < 4; ++mt){
#pragma unroll
      for (int r = 0; r < 4; ++r){
        int o = mt*16 + g*4 + r;
        float v = acc[j][mt][r];
        float u  = v * (0.7978845608028654f + 0.03567740814f * v * v);
        float au = fabsf(u);
        float e  = __expf(-2.f*au);
        float th = (1.f - e) * __builtin_amdgcn_rcpf(1.f + e);
        th = copysignf(th, u);
        ob[(size_t)o*65536 + w] = 0.5f*v*(1.f + th);
      }
    }
  }
}

extern "C" void kernel_launch(void* const* d_in, const int* in_sizes, int n_in,
                              void* d_out, int out_size, void* d_ws, size_t ws_size,
                              hipStream_t stream) {
  const float* x   = (const float*)d_in[0];
  const float* wre = (const float*)d_in[1];
  const float* wim = (const float*)d_in[2];
  const float* cw  = (const float*)d_in[3];
  const float* cb  = (const float*)d_in[4];
  float* out = (float*)d_out;
  float* ws  = (float*)d_ws;

  float*    twA  = ws + TWA_OFF;
  float*    twB  = ws + TWB_OFF;
  unsigned* trgT = (unsigned*)(ws + TRG_OFF);
  float*    X    = ws + X_OFF;
  float*    OF   = ws + OF_OFF;
  unsigned* Zpk  = (unsigned*)(ws + Z_OFF);

  k_init <<<20,   256, 0, stream>>>(twA, twB, trgT);
  k_fwd  <<<1024, 256, 0, stream>>>(x, twA, twB, X);
  k_mix  <<<400,  256, 0, stream>>>(X, wre, wim, OF);
  k_idfth<<<1024, 256, 0, stream>>>(OF, Zpk);
  k_out  <<<4096, 256, 0, stream>>>(x, Zpk, trgT, cw, cb, out);
}